// Round 9
// baseline (336.910 us; speedup 1.0000x reference)
//
#include <hip/hip_runtime.h>
#include <hip/hip_fp16.h>

#define EPS      1e-7f
#define MAX_TANH 15.0f
#define MAXNORM  0.99999f   // (1 - 1e-5) / sqrt(c), c = 1
#define ART_CLIP 0.99999f   // 1 - 1e-5
#define HGRID    512        // coarse-partition blocks (histogram & scatter)
#define CAPF     8192       // fine-pass LDS staging capacity (avg bucket ~6.1K)

__device__ __forceinline__ float wave_sum64(float v) {
#pragma unroll
    for (int o = 32; o > 0; o >>= 1) v += __shfl_xor(v, o, 64);
    return v;
}

__device__ __forceinline__ float gsum16(float v) {
    v += __shfl_xor(v, 1, 64);
    v += __shfl_xor(v, 2, 64);
    v += __shfl_xor(v, 4, 64);
    v += __shfl_xor(v, 8, 64);
    return v;
}

__device__ __forceinline__ float clamp_tanh_arg(float x) {
    return fminf(fmaxf(x, -MAX_TANH), MAX_TANH);
}

__device__ __forceinline__ float artanh_clip(float x) {
    x = fminf(fmaxf(x, -ART_CLIP), ART_CLIP);
    return 0.5f * logf((1.0f + x) / (1.0f - x));
}

// fma a half4 (as uint2) * m into acc
__device__ __forceinline__ void fma_h4(float4& acc, uint2 u, float m) {
    float2 f01 = __half22float2(*reinterpret_cast<__half2*>(&u.x));
    float2 f23 = __half22float2(*reinterpret_cast<__half2*>(&u.y));
    acc.x = fmaf(f01.x, m, acc.x); acc.y = fmaf(f01.y, m, acc.y);
    acc.z = fmaf(f23.x, m, acc.z); acc.w = fmaf(f23.y, m, acc.w);
}

// ---------------------------------------------------------------------------
// K1 (fat). Blocks [0, HGRID): coarse histogram of row>>8 into LDS (no global
// atomics), coalesced write of per-block counts histB[blk*nb + b].
// Blocks [HGRID, ...): layer-1 transform (fp16 tangent output):
//   ht = logmap0(proj(mobius_add(proj(mobius_matvec(W,x)), hyp_bias)))
// ---------------------------------------------------------------------------
__global__ __launch_bounds__(256) void hist_transform_kernel(
    const int* __restrict__ rows, int* __restrict__ histB,
    int n_edges, int epb, int nb,
    const float* __restrict__ x, const float* __restrict__ W,
    const float* __restrict__ b, __half* __restrict__ ht, int n_nodes)
{
    __shared__ float WT[64 * 65];
    __shared__ float xs[4][64];
    __shared__ int hh[256];

    if (blockIdx.x < HGRID) {
        const int b0 = blockIdx.x * epb;
        const int b1 = min(b0 + epb, n_edges);
        if (threadIdx.x < 256) hh[threadIdx.x] = 0;
        __syncthreads();
        for (int i = b0 + threadIdx.x; i < b1; i += 256)
            atomicAdd(&hh[rows[i] >> 8], 1);
        __syncthreads();
        if (threadIdx.x < nb)
            histB[blockIdx.x * nb + threadIdx.x] = hh[threadIdx.x];
        return;
    }

    // ---------------- transform half ----------------
    const int t = threadIdx.x;
    const int lane = t & 63;
    const int wv = t >> 6;
    const int bid = blockIdx.x - HGRID;
    const int tgrid = gridDim.x - HGRID;

#pragma unroll
    for (int r = 0; r < 16; ++r) {
        int idx = r * 256 + t;
        WT[(idx & 63) * 65 + (idx >> 6)] = W[idx];
    }
    __syncthreads();

    // hyp_bias = proj(expmap0(b)); |expmap0(b)| = tanh(|b|)
    float bj = b[lane];
    float bn = fmaxf(sqrtf(wave_sum64(bj * bj)), EPS);
    float tb = tanhf(clamp_tanh_arg(bn));
    float hb = tb * bj / bn;
    if (tb > MAXNORM) { hb *= MAXNORM / tb; tb = MAXNORM; }
    const float y2 = tb * tb;

    for (long long base = (long long)bid * 4; base < n_nodes;
         base += (long long)tgrid * 4) {
        long long node = base + wv;
        float xj = 0.0f;
        if (node < n_nodes) xj = x[node * 64 + lane];
        xs[wv][lane] = xj;

        float mxj = 0.0f;
#pragma unroll
        for (int k = 0; k < 64; ++k)
            mxj = fmaf(xs[wv][k], WT[k * 65 + lane], mxj);

        float xn  = fmaxf(sqrtf(wave_sum64(xj * xj)), EPS);
        float mxn = fmaxf(sqrtf(wave_sum64(mxj * mxj)), EPS);
        float r = tanhf(clamp_tanh_arg(mxn / xn * artanh_clip(xn)));  // = |h|
        float hj = r * mxj / mxn;
        float hn = fmaxf(r, EPS);
        if (hn > MAXNORM) { hj *= MAXNORM / hn; hn = MAXNORM; }

        float x2 = hn * hn;
        float xy = wave_sum64(hj * hb);
        float num = (1.0f + 2.0f * xy + y2) * hj + (1.0f - x2) * hb;
        float den = fmaxf(1.0f + 2.0f * xy + x2 * y2, EPS);
        hj = num / den;

        float hn2 = fmaxf(sqrtf(wave_sum64(hj * hj)), EPS);
        if (hn2 > MAXNORM) { hj *= MAXNORM / hn2; hn2 = MAXNORM; }

        float htj = artanh_clip(hn2) * hj / hn2;   // logmap0

        if (node < n_nodes) ht[node * 64 + lane] = __float2half(htj);
    }
}

// ---------------------------------------------------------------------------
// K2: hierarchical scan (single block). Produces bucket_base[nb+1] and
// rewrites histB in place into per-(block,bucket) exclusive global offsets.
// ---------------------------------------------------------------------------
__global__ __launch_bounds__(1024) void scan2_kernel(
    int* __restrict__ histB, int* __restrict__ bucket_base, int nb)
{
    __shared__ int part4[1024];
    __shared__ int tot[256], orig[256], base[256];
    const int t = threadIdx.x;
    const int lane = t & 63, wid = t >> 6;

    // per-bucket totals (4 partials per bucket over HGRID/4 blocks each)
    int sum = 0;
    if (t < nb * 4) {
        int b = t >> 2, p = t & 3;
        const int per = HGRID >> 2;
        for (int i = p * per; i < (p + 1) * per; ++i)
            sum += histB[i * nb + b];
    }
    part4[t] = sum;
    __syncthreads();
    if (t < 256) {
        int s4 = (t < nb) ? (part4[t*4] + part4[t*4+1] + part4[t*4+2] + part4[t*4+3]) : 0;
        tot[t] = s4; orig[t] = s4;
    }
    __syncthreads();
    // inclusive Hillis-Steele over 256
    for (int off = 1; off < 256; off <<= 1) {
        int v = 0;
        if (t < 256 && t >= off) v = tot[t - off];
        __syncthreads();
        if (t < 256) tot[t] += v;
        __syncthreads();
    }
    if (t < nb) {
        base[t] = tot[t] - orig[t];
        bucket_base[t] = base[t];
    }
    if (t == 0) bucket_base[nb] = tot[nb - 1];
    __syncthreads();

    // per-bucket running offsets over blocks (one wave per bucket)
    for (int b = wid; b < nb; b += 16) {
        int carry = base[b];
        for (int c0 = 0; c0 < HGRID; c0 += 64) {
            int idx = (c0 + lane) * nb + b;
            int v = histB[idx];
            int incl = v;
#pragma unroll
            for (int o = 1; o < 64; o <<= 1) {
                int tt = __shfl_up(incl, o, 64);
                if (lane >= o) incl += tt;
            }
            histB[idx] = carry + incl - v;   // exclusive + carry
            carry += __shfl(incl, 63, 64);
        }
    }
}

// ---------------------------------------------------------------------------
// K3: coarse scatter via LDS cursors (no global atomics). Each block writes
// its edges grouped into nb contiguous chunks (~10 edges each): ~nb line txns
// per block instead of one random line per edge.
// Record: x = (row<<16)|col (both < 65536), y = mask bits.
// ---------------------------------------------------------------------------
__global__ __launch_bounds__(256) void coarse_scatter_kernel(
    const int* __restrict__ rows, const int* __restrict__ cols,
    const float* __restrict__ edge_mask, const int* __restrict__ off,
    int2* __restrict__ coarse, int n_edges, int epb, int nb)
{
    __shared__ int cur[256];
    const int b0 = blockIdx.x * epb;
    const int b1 = min(b0 + epb, n_edges);
    if (threadIdx.x < nb) cur[threadIdx.x] = off[blockIdx.x * nb + threadIdx.x];
    __syncthreads();
    for (int i = b0 + threadIdx.x; i < b1; i += 256) {
        int r = rows[i], c = cols[i];
        float m = edge_mask[i];
        int pos = atomicAdd(&cur[r >> 8], 1);
        coarse[pos] = make_int2((r << 16) | c, __float_as_int(m));
    }
}

// ---------------------------------------------------------------------------
// K4: fine partition. One block per coarse bucket (~6.1K edges, 256 rows):
// LDS histogram -> LDS scan -> LDS scatter -> fully coalesced CSR write.
// Also writes row_start[] (and row_start[N]=E).
// ---------------------------------------------------------------------------
__global__ __launch_bounds__(1024) void fine_kernel(
    const int2* __restrict__ coarse, const int* __restrict__ bucket_base,
    int2* __restrict__ csr, int* __restrict__ row_start, int n_nodes, int n_edges)
{
    __shared__ int hh[256], incl[256], curs[256];
    __shared__ int2 out[CAPF];
    const int t = threadIdx.x;
    const int b = blockIdx.x;
    const int bbase = bucket_base[b];
    const int n_e = bucket_base[b + 1] - bbase;

    if (t < 256) hh[t] = 0;
    __syncthreads();
    for (int i = t; i < n_e; i += 1024) {
        unsigned rx = (unsigned)coarse[bbase + i].x;
        atomicAdd(&hh[(rx >> 16) & 255], 1);
    }
    __syncthreads();
    if (t < 256) incl[t] = hh[t];
    __syncthreads();
    for (int off = 1; off < 256; off <<= 1) {
        int v = 0;
        if (t < 256 && t >= off) v = incl[t - off];
        __syncthreads();
        if (t < 256) incl[t] += v;
        __syncthreads();
    }
    if (t < 256) {
        int lstart = incl[t] - hh[t];
        curs[t] = lstart;
        int grow = (b << 8) + t;
        if (grow < n_nodes) row_start[grow] = bbase + lstart;
    }
    if (b == gridDim.x - 1 && t == 0) row_start[n_nodes] = n_edges;
    __syncthreads();
    for (int i = t; i < n_e; i += 1024) {
        int2 rec = coarse[bbase + i];
        unsigned rx = (unsigned)rec.x;
        int slot = atomicAdd(&curs[(rx >> 16) & 255], 1);
        if (slot < CAPF) out[slot] = make_int2((int)(rx & 0xffffu), rec.y);
    }
    __syncthreads();
    const int lim = min(n_e, CAPF);
    for (int i = t; i < lim; i += 1024)
        csr[bbase + i] = out[i];
}

// ---------------------------------------------------------------------------
// Gather + finish: 4 nodes per wave, 16 lanes per node, 4 dims (8 B fp16) per
// lane; CSR (row_start) adjacency. If FUSE: next layer's HypLinear + logmap0,
// fp16 output; else fp32 final output.
// ---------------------------------------------------------------------------
template <bool FUSE>
__global__ __launch_bounds__(256) void gather_kernel(
    const __half* __restrict__ ht, const int2* __restrict__ csr,
    const int* __restrict__ row_start, const float* __restrict__ node_mask,
    const float* __restrict__ W, const float* __restrict__ b,
    void* __restrict__ outp, int n_nodes)
{
    __shared__ float WT[FUSE ? 4096 : 1];     // WT[(k<<6)|(j^4(k&15))] = W[j][k]
    __shared__ float xs[FUSE ? 16 * 68 : 1];  // stride 68: conflict-free bcast

    const int t = threadIdx.x;
    const int lane = t & 63;
    const int wv = t >> 6;
    const int ns = lane >> 4;    // node sub 0..3
    const int q  = lane & 15;    // dim quad: dims 4q..4q+3

    float4 hb4 = make_float4(0.f, 0.f, 0.f, 0.f);
    float y2 = 0.f;
    if constexpr (FUSE) {
#pragma unroll
        for (int r = 0; r < 16; ++r) {
            int idx = r * 256 + t;
            int j = idx >> 6, k = idx & 63;
            WT[(k << 6) | (j ^ ((k & 15) << 2))] = W[idx];
        }
        float4 b4 = ((const float4*)b)[q];
        float ssb = b4.x*b4.x + b4.y*b4.y + b4.z*b4.z + b4.w*b4.w;
        float bn = fmaxf(sqrtf(gsum16(ssb)), EPS);
        float tb = tanhf(clamp_tanh_arg(bn));
        float sb = tb / bn;
        hb4.x = b4.x * sb; hb4.y = b4.y * sb; hb4.z = b4.z * sb; hb4.w = b4.w * sb;
        if (tb > MAXNORM) {
            float sc = MAXNORM / tb;
            hb4.x *= sc; hb4.y *= sc; hb4.z *= sc; hb4.w *= sc;
            tb = MAXNORM;
        }
        y2 = tb * tb;
        __syncthreads();
    }

    const int node = blockIdx.x * 16 + (wv << 2) + ns;
    const bool valid = node < n_nodes;
    const int nd = valid ? node : (n_nodes - 1);
    const int s = row_start[nd];
    const int e = row_start[nd + 1];

    float4 acc = make_float4(0.f, 0.f, 0.f, 0.f);
    float msum = 0.f;
    int j = s;
    for (; j + 4 <= e; j += 4) {
        int2 c0 = csr[j], c1 = csr[j + 1];
        int2 c2 = csr[j + 2], c3 = csr[j + 3];
        uint2 u0 = *((const uint2*)(ht + (long long)c0.x * 64) + q);
        uint2 u1 = *((const uint2*)(ht + (long long)c1.x * 64) + q);
        uint2 u2 = *((const uint2*)(ht + (long long)c2.x * 64) + q);
        uint2 u3 = *((const uint2*)(ht + (long long)c3.x * 64) + q);
        float m0 = __int_as_float(c0.y), m1 = __int_as_float(c1.y);
        float m2 = __int_as_float(c2.y), m3 = __int_as_float(c3.y);
        fma_h4(acc, u0, m0);
        fma_h4(acc, u1, m1);
        fma_h4(acc, u2, m2);
        fma_h4(acc, u3, m3);
        msum += m0 + m1 + m2 + m3;
    }
    for (; j < e; ++j) {
        int2 cm = csr[j];
        uint2 u = *((const uint2*)(ht + (long long)cm.x * 64) + q);
        float m = __int_as_float(cm.y);
        fma_h4(acc, u, m);
        msum += m;
    }

    const float inv = 1.0f / fmaxf(msum, 1.0f);
    acc.x *= inv; acc.y *= inv; acc.z *= inv; acc.w *= inv;

    // ---- finish: proj(expmap0(relu(logmap0(proj(expmap0(agg)))))) * nm ----
    float ss = acc.x*acc.x + acc.y*acc.y + acc.z*acc.z + acc.w*acc.w;
    float n1 = fmaxf(sqrtf(gsum16(ss)), EPS);
    float t1 = tanhf(clamp_tanh_arg(n1));
    float r1 = t1 / n1;
    acc.x *= r1; acc.y *= r1; acc.z *= r1; acc.w *= r1;
    if (t1 > MAXNORM) {
        float sc = MAXNORM / t1;
        acc.x *= sc; acc.y *= sc; acc.z *= sc; acc.w *= sc;
        t1 = MAXNORM;
    }
    float n2 = fmaxf(t1, EPS);
    float r2 = artanh_clip(n2) / n2;
    acc.x = fmaxf(acc.x * r2, 0.f); acc.y = fmaxf(acc.y * r2, 0.f);
    acc.z = fmaxf(acc.z * r2, 0.f); acc.w = fmaxf(acc.w * r2, 0.f);

    ss = acc.x*acc.x + acc.y*acc.y + acc.z*acc.z + acc.w*acc.w;
    float n3 = fmaxf(sqrtf(gsum16(ss)), EPS);
    float t3 = tanhf(clamp_tanh_arg(n3));
    float r3 = t3 / n3;
    acc.x *= r3; acc.y *= r3; acc.z *= r3; acc.w *= r3;
    if (t3 > MAXNORM) {
        float sc = MAXNORM / t3;
        acc.x *= sc; acc.y *= sc; acc.z *= sc; acc.w *= sc;
        t3 = MAXNORM;
    }

    const float nm = node_mask[nd];
    acc.x *= nm; acc.y *= nm; acc.z *= nm; acc.w *= nm;

    if constexpr (!FUSE) {
        if (valid) ((float4*)((float*)outp + (long long)node * 64))[q] = acc;
    } else {
        // ---- fused next-layer HypLinear + logmap0, fp16 output ----
        float* xrow = &xs[(wv * 4 + ns) * 68];      // wave-private row
        *(float4*)(xrow + (q << 2)) = acc;          // in-wave LDS ordering ok

        float4 mx = make_float4(0.f, 0.f, 0.f, 0.f);
#pragma unroll
        for (int k = 0; k < 64; ++k) {
            float xk = xrow[k];
            const float4 w4 = *(const float4*)&WT[(k << 6) | ((q << 2) ^ ((k & 15) << 2))];
            mx.x = fmaf(w4.x, xk, mx.x); mx.y = fmaf(w4.y, xk, mx.y);
            mx.z = fmaf(w4.z, xk, mx.z); mx.w = fmaf(w4.w, xk, mx.w);
        }

        float xn  = fmaxf(t3 * fabsf(nm), EPS);     // |x| known analytically
        float ssm = mx.x*mx.x + mx.y*mx.y + mx.z*mx.z + mx.w*mx.w;
        float mxn = fmaxf(sqrtf(gsum16(ssm)), EPS);
        float r = tanhf(clamp_tanh_arg(mxn / xn * artanh_clip(xn)));
        float rs = r / mxn;
        float4 hj = make_float4(mx.x * rs, mx.y * rs, mx.z * rs, mx.w * rs);
        float hn = fmaxf(r, EPS);
        if (hn > MAXNORM) {
            float sc = MAXNORM / hn;
            hj.x *= sc; hj.y *= sc; hj.z *= sc; hj.w *= sc;
            hn = MAXNORM;
        }

        float x2 = hn * hn;
        float xy = gsum16(hj.x*hb4.x + hj.y*hb4.y + hj.z*hb4.z + hj.w*hb4.w);
        float ca = 1.0f + 2.0f * xy + y2;
        float cb = 1.0f - x2;
        float iden = 1.0f / fmaxf(1.0f + 2.0f * xy + x2 * y2, EPS);
        hj.x = (ca * hj.x + cb * hb4.x) * iden;
        hj.y = (ca * hj.y + cb * hb4.y) * iden;
        hj.z = (ca * hj.z + cb * hb4.z) * iden;
        hj.w = (ca * hj.w + cb * hb4.w) * iden;

        float ssh = hj.x*hj.x + hj.y*hj.y + hj.z*hj.z + hj.w*hj.w;
        float hn2 = fmaxf(sqrtf(gsum16(ssh)), EPS);
        float sc2 = (hn2 > MAXNORM) ? (MAXNORM / hn2) : 1.0f;
        float hnc = fminf(hn2, MAXNORM);
        float lr = artanh_clip(hnc) / hnc * sc2;    // logmap0 incl. proj scale
        hj.x *= lr; hj.y *= lr; hj.z *= lr; hj.w *= lr;

        if (valid) {
            __half2 p01 = __float22half2_rn(make_float2(hj.x, hj.y));
            __half2 p23 = __float22half2_rn(make_float2(hj.z, hj.w));
            uint2 o;
            o.x = *reinterpret_cast<unsigned*>(&p01);
            o.y = *reinterpret_cast<unsigned*>(&p23);
            *((uint2*)((__half*)outp + (long long)node * 64) + q) = o;
        }
    }
}

extern "C" void kernel_launch(void* const* d_in, const int* in_sizes, int n_in,
                              void* d_out, int out_size, void* d_ws, size_t ws_size,
                              hipStream_t stream) {
    const float* h         = (const float*)d_in[0];
    // d_in[1] = distances (unused by the reference computation)
    const int*   edges     = (const int*)d_in[2];     // [2, E] int32
    const float* node_mask = (const float*)d_in[3];
    const float* edge_mask = (const float*)d_in[4];
    const float* W0        = (const float*)d_in[5];
    const float* b0        = (const float*)d_in[6];
    const float* W1        = (const float*)d_in[7];
    const float* b1        = (const float*)d_in[8];
    float* out = (float*)d_out;

    const int N = in_sizes[0] / 64;
    const int E = in_sizes[4];          // edge_mask is [E,1]
    const int* rows = edges;
    const int* cols = edges + E;

    const int NB  = (N + 255) >> 8;     // coarse buckets (row>>8), 196 for 50K
    const int EPB = (E + HGRID - 1) / HGRID;

    size_t nd = (size_t)N * 64;
    char* ws = (char*)d_ws;
    __half* B1         = (__half*)ws; ws += nd * sizeof(__half);        // ht1 fp16
    __half* B2         = (__half*)ws; ws += nd * sizeof(__half);        // ht2 fp16
    int2*  coarse      = (int2*)ws;   ws += (size_t)E * sizeof(int2);
    int2*  csr         = (int2*)ws;   ws += (size_t)E * sizeof(int2);
    int*   histB       = (int*)ws;    ws += (size_t)HGRID * NB * sizeof(int);
    int*   bucket_base = (int*)ws;    ws += (size_t)(NB + 1) * sizeof(int);
    int*   row_start   = (int*)ws;    ws += (size_t)(N + 1) * sizeof(int);

    const int TGRID = 1024;
    const int NGRID = (N + 15) / 16;

    // K1: coarse histogram (no global atomics) + layer-1 transform
    hist_transform_kernel<<<HGRID + TGRID, 256, 0, stream>>>(
        rows, histB, E, EPB, NB, h, W0, b0, B1, N);

    // K2: hierarchical scan -> bucket_base + per-(block,bucket) offsets
    scan2_kernel<<<1, 1024, 0, stream>>>(histB, bucket_base, NB);

    // K3: coarse scatter with LDS cursors (contiguous per-block chunks)
    coarse_scatter_kernel<<<HGRID, 256, 0, stream>>>(
        rows, cols, edge_mask, histB, coarse, E, EPB, NB);

    // K4: fine partition -> CSR + row_start (fully coalesced global I/O)
    fine_kernel<<<NB, 1024, 0, stream>>>(
        coarse, bucket_base, csr, row_start, N, E);

    // layer-1 agg+finish fused with layer-2 HypLinear -> ht2 (fp16)
    gather_kernel<true><<<NGRID, 256, 0, stream>>>(
        B1, csr, row_start, node_mask, W1, b1, B2, N);

    // layer-2 agg+finish -> final fp32 output
    gather_kernel<false><<<NGRID, 256, 0, stream>>>(
        B2, csr, row_start, node_mask, nullptr, nullptr, out, N);
}

// Round 10
// 222.169 us; speedup vs baseline: 1.5165x; 1.5165x over previous
//
#include <hip/hip_runtime.h>
#include <hip/hip_fp16.h>

#define EPS      1e-7f
#define MAX_TANH 15.0f
#define MAXNORM  0.99999f   // (1 - 1e-5) / sqrt(c), c = 1
#define ART_CLIP 0.99999f   // 1 - 1e-5
#define HGRID    512        // coarse-partition blocks (histogram & scatter)
#define CAPF     8192       // fine-pass LDS staging capacity (avg bucket ~6.1K)

__device__ __forceinline__ float wave_sum64(float v) {
#pragma unroll
    for (int o = 32; o > 0; o >>= 1) v += __shfl_xor(v, o, 64);
    return v;
}

__device__ __forceinline__ float gsum16(float v) {
    v += __shfl_xor(v, 1, 64);
    v += __shfl_xor(v, 2, 64);
    v += __shfl_xor(v, 4, 64);
    v += __shfl_xor(v, 8, 64);
    return v;
}

__device__ __forceinline__ float clamp_tanh_arg(float x) {
    return fminf(fmaxf(x, -MAX_TANH), MAX_TANH);
}

__device__ __forceinline__ float artanh_clip(float x) {
    x = fminf(fmaxf(x, -ART_CLIP), ART_CLIP);
    return 0.5f * logf((1.0f + x) / (1.0f - x));
}

// fma a half4 (as uint2) * m into acc
__device__ __forceinline__ void fma_h4(float4& acc, uint2 u, float m) {
    float2 f01 = __half22float2(*reinterpret_cast<__half2*>(&u.x));
    float2 f23 = __half22float2(*reinterpret_cast<__half2*>(&u.y));
    acc.x = fmaf(f01.x, m, acc.x); acc.y = fmaf(f01.y, m, acc.y);
    acc.z = fmaf(f23.x, m, acc.z); acc.w = fmaf(f23.y, m, acc.w);
}

// ---------------------------------------------------------------------------
// K1 (fat). Blocks [0, HGRID): coarse histogram of row>>8 into LDS (no global
// atomics), coalesced write of per-block counts histB[blk*nb + b].
// Blocks [HGRID, ...): layer-1 transform (fp16 tangent output):
//   ht = logmap0(proj(mobius_add(proj(mobius_matvec(W,x)), hyp_bias)))
// ---------------------------------------------------------------------------
__global__ __launch_bounds__(256) void hist_transform_kernel(
    const int* __restrict__ rows, int* __restrict__ histB,
    int n_edges, int epb, int nb,
    const float* __restrict__ x, const float* __restrict__ W,
    const float* __restrict__ b, __half* __restrict__ ht, int n_nodes)
{
    __shared__ float WT[64 * 65];
    __shared__ float xs[4][64];
    __shared__ int hh[256];

    if (blockIdx.x < HGRID) {
        const int b0 = blockIdx.x * epb;
        const int b1 = min(b0 + epb, n_edges);
        if (threadIdx.x < 256) hh[threadIdx.x] = 0;
        __syncthreads();
        for (int i = b0 + threadIdx.x; i < b1; i += 256)
            atomicAdd(&hh[rows[i] >> 8], 1);
        __syncthreads();
        if (threadIdx.x < nb)
            histB[blockIdx.x * nb + threadIdx.x] = hh[threadIdx.x];
        return;
    }

    // ---------------- transform half ----------------
    const int t = threadIdx.x;
    const int lane = t & 63;
    const int wv = t >> 6;
    const int bid = blockIdx.x - HGRID;
    const int tgrid = gridDim.x - HGRID;

#pragma unroll
    for (int r = 0; r < 16; ++r) {
        int idx = r * 256 + t;
        WT[(idx & 63) * 65 + (idx >> 6)] = W[idx];
    }
    __syncthreads();

    // hyp_bias = proj(expmap0(b)); |expmap0(b)| = tanh(|b|)
    float bj = b[lane];
    float bn = fmaxf(sqrtf(wave_sum64(bj * bj)), EPS);
    float tb = tanhf(clamp_tanh_arg(bn));
    float hb = tb * bj / bn;
    if (tb > MAXNORM) { hb *= MAXNORM / tb; tb = MAXNORM; }
    const float y2 = tb * tb;

    for (long long base = (long long)bid * 4; base < n_nodes;
         base += (long long)tgrid * 4) {
        long long node = base + wv;
        float xj = 0.0f;
        if (node < n_nodes) xj = x[node * 64 + lane];
        xs[wv][lane] = xj;

        float mxj = 0.0f;
#pragma unroll
        for (int k = 0; k < 64; ++k)
            mxj = fmaf(xs[wv][k], WT[k * 65 + lane], mxj);

        float xn  = fmaxf(sqrtf(wave_sum64(xj * xj)), EPS);
        float mxn = fmaxf(sqrtf(wave_sum64(mxj * mxj)), EPS);
        float r = tanhf(clamp_tanh_arg(mxn / xn * artanh_clip(xn)));  // = |h|
        float hj = r * mxj / mxn;
        float hn = fmaxf(r, EPS);
        if (hn > MAXNORM) { hj *= MAXNORM / hn; hn = MAXNORM; }

        float x2 = hn * hn;
        float xy = wave_sum64(hj * hb);
        float num = (1.0f + 2.0f * xy + y2) * hj + (1.0f - x2) * hb;
        float den = fmaxf(1.0f + 2.0f * xy + x2 * y2, EPS);
        hj = num / den;

        float hn2 = fmaxf(sqrtf(wave_sum64(hj * hj)), EPS);
        if (hn2 > MAXNORM) { hj *= MAXNORM / hn2; hn2 = MAXNORM; }

        float htj = artanh_clip(hn2) * hj / hn2;   // logmap0

        if (node < n_nodes) ht[node * 64 + lane] = __float2half(htj);
    }
}

// ---------------------------------------------------------------------------
// K2a: one block per coarse bucket. Scan the bucket's HGRID per-block counts
// (histB[i*nb + b], i in [0,HGRID)) into within-bucket exclusive offsets
// (in place) and write the bucket total.
// ---------------------------------------------------------------------------
__global__ __launch_bounds__(HGRID) void scan_bucket_kernel(
    int* __restrict__ histB, int* __restrict__ tot, int nb)
{
    __shared__ int wsum[8];                 // HGRID/64 = 8 waves
    const int b = blockIdx.x;
    const int t = threadIdx.x;
    const int lane = t & 63, wid = t >> 6;
    int v = histB[t * nb + b];
    int incl = v;
#pragma unroll
    for (int o = 1; o < 64; o <<= 1) {
        int tt = __shfl_up(incl, o, 64);
        if (lane >= o) incl += tt;
    }
    if (lane == 63) wsum[wid] = incl;
    __syncthreads();
    if (wid == 0 && lane < 8) {
        int ws = wsum[lane];
#pragma unroll
        for (int o = 1; o < 8; o <<= 1) {
            int tt = __shfl_up(ws, o, 64);
            if (lane >= o) ws += tt;
        }
        wsum[lane] = ws;
    }
    __syncthreads();
    int base = (wid > 0) ? wsum[wid - 1] : 0;
    histB[t * nb + b] = base + incl - v;    // within-bucket exclusive
    if (t == HGRID - 1) tot[b] = base + incl;
}

// ---------------------------------------------------------------------------
// K2b: tiny single-block scan of bucket totals -> bucket_base[nb+1].
// ---------------------------------------------------------------------------
__global__ __launch_bounds__(256) void scan_base_kernel(
    const int* __restrict__ tot, int* __restrict__ bucket_base, int nb)
{
    __shared__ int s[256];
    const int t = threadIdx.x;
    int v = (t < nb) ? tot[t] : 0;
    s[t] = v;
    __syncthreads();
    for (int off = 1; off < 256; off <<= 1) {
        int u = (t >= off) ? s[t - off] : 0;
        __syncthreads();
        s[t] += u;
        __syncthreads();
    }
    if (t < nb) bucket_base[t] = s[t] - v;
    if (t == nb - 1) bucket_base[nb] = s[t];
}

// ---------------------------------------------------------------------------
// K3: coarse scatter via LDS cursors (no global atomics). cursor = global
// bucket base + within-bucket per-block offset. Each block writes its edges
// grouped into nb contiguous chunks.
// Record: x = (row<<16)|col (both < 65536), y = mask bits.
// ---------------------------------------------------------------------------
__global__ __launch_bounds__(256) void coarse_scatter_kernel(
    const int* __restrict__ rows, const int* __restrict__ cols,
    const float* __restrict__ edge_mask, const int* __restrict__ off,
    const int* __restrict__ bucket_base,
    int2* __restrict__ coarse, int n_edges, int epb, int nb)
{
    __shared__ int cur[256];
    const int b0 = blockIdx.x * epb;
    const int b1 = min(b0 + epb, n_edges);
    if (threadIdx.x < nb)
        cur[threadIdx.x] = bucket_base[threadIdx.x] + off[blockIdx.x * nb + threadIdx.x];
    __syncthreads();
    for (int i = b0 + threadIdx.x; i < b1; i += 256) {
        int r = rows[i], c = cols[i];
        float m = edge_mask[i];
        int pos = atomicAdd(&cur[r >> 8], 1);
        coarse[pos] = make_int2((r << 16) | c, __float_as_int(m));
    }
}

// ---------------------------------------------------------------------------
// K4: fine partition. One block per coarse bucket (~6.1K edges, 256 rows):
// LDS histogram -> LDS scan -> LDS scatter -> fully coalesced CSR write.
// Also writes row_start[] (and row_start[N]=E).
// ---------------------------------------------------------------------------
__global__ __launch_bounds__(1024) void fine_kernel(
    const int2* __restrict__ coarse, const int* __restrict__ bucket_base,
    int2* __restrict__ csr, int* __restrict__ row_start, int n_nodes, int n_edges)
{
    __shared__ int hh[256], incl[256], curs[256];
    __shared__ int2 out[CAPF];
    const int t = threadIdx.x;
    const int b = blockIdx.x;
    const int bbase = bucket_base[b];
    const int n_e = bucket_base[b + 1] - bbase;

    if (t < 256) hh[t] = 0;
    __syncthreads();
    for (int i = t; i < n_e; i += 1024) {
        unsigned rx = (unsigned)coarse[bbase + i].x;
        atomicAdd(&hh[(rx >> 16) & 255], 1);
    }
    __syncthreads();
    if (t < 256) incl[t] = hh[t];
    __syncthreads();
    for (int off = 1; off < 256; off <<= 1) {
        int v = 0;
        if (t < 256 && t >= off) v = incl[t - off];
        __syncthreads();
        if (t < 256) incl[t] += v;
        __syncthreads();
    }
    if (t < 256) {
        int lstart = incl[t] - hh[t];
        curs[t] = lstart;
        int grow = (b << 8) + t;
        if (grow < n_nodes) row_start[grow] = bbase + lstart;
    }
    if (b == gridDim.x - 1 && t == 0) row_start[n_nodes] = n_edges;
    __syncthreads();
    for (int i = t; i < n_e; i += 1024) {
        int2 rec = coarse[bbase + i];
        unsigned rx = (unsigned)rec.x;
        int slot = atomicAdd(&curs[(rx >> 16) & 255], 1);
        if (slot < CAPF) out[slot] = make_int2((int)(rx & 0xffffu), rec.y);
    }
    __syncthreads();
    const int lim = min(n_e, CAPF);
    for (int i = t; i < lim; i += 1024)
        csr[bbase + i] = out[i];
}

// ---------------------------------------------------------------------------
// Gather + finish: 4 nodes per wave, 16 lanes per node, 4 dims (8 B fp16) per
// lane; CSR (row_start) adjacency. If FUSE: next layer's HypLinear + logmap0,
// fp16 output; else fp32 final output.
// ---------------------------------------------------------------------------
template <bool FUSE>
__global__ __launch_bounds__(256) void gather_kernel(
    const __half* __restrict__ ht, const int2* __restrict__ csr,
    const int* __restrict__ row_start, const float* __restrict__ node_mask,
    const float* __restrict__ W, const float* __restrict__ b,
    void* __restrict__ outp, int n_nodes)
{
    __shared__ float WT[FUSE ? 4096 : 1];     // WT[(k<<6)|(j^4(k&15))] = W[j][k]
    __shared__ float xs[FUSE ? 16 * 68 : 1];  // stride 68: conflict-free bcast

    const int t = threadIdx.x;
    const int lane = t & 63;
    const int wv = t >> 6;
    const int ns = lane >> 4;    // node sub 0..3
    const int q  = lane & 15;    // dim quad: dims 4q..4q+3

    float4 hb4 = make_float4(0.f, 0.f, 0.f, 0.f);
    float y2 = 0.f;
    if constexpr (FUSE) {
#pragma unroll
        for (int r = 0; r < 16; ++r) {
            int idx = r * 256 + t;
            int j = idx >> 6, k = idx & 63;
            WT[(k << 6) | (j ^ ((k & 15) << 2))] = W[idx];
        }
        float4 b4 = ((const float4*)b)[q];
        float ssb = b4.x*b4.x + b4.y*b4.y + b4.z*b4.z + b4.w*b4.w;
        float bn = fmaxf(sqrtf(gsum16(ssb)), EPS);
        float tb = tanhf(clamp_tanh_arg(bn));
        float sb = tb / bn;
        hb4.x = b4.x * sb; hb4.y = b4.y * sb; hb4.z = b4.z * sb; hb4.w = b4.w * sb;
        if (tb > MAXNORM) {
            float sc = MAXNORM / tb;
            hb4.x *= sc; hb4.y *= sc; hb4.z *= sc; hb4.w *= sc;
            tb = MAXNORM;
        }
        y2 = tb * tb;
        __syncthreads();
    }

    const int node = blockIdx.x * 16 + (wv << 2) + ns;
    const bool valid = node < n_nodes;
    const int nd = valid ? node : (n_nodes - 1);
    const int s = row_start[nd];
    const int e = row_start[nd + 1];

    float4 acc = make_float4(0.f, 0.f, 0.f, 0.f);
    float msum = 0.f;
    int j = s;
    for (; j + 4 <= e; j += 4) {
        int2 c0 = csr[j], c1 = csr[j + 1];
        int2 c2 = csr[j + 2], c3 = csr[j + 3];
        uint2 u0 = *((const uint2*)(ht + (long long)c0.x * 64) + q);
        uint2 u1 = *((const uint2*)(ht + (long long)c1.x * 64) + q);
        uint2 u2 = *((const uint2*)(ht + (long long)c2.x * 64) + q);
        uint2 u3 = *((const uint2*)(ht + (long long)c3.x * 64) + q);
        float m0 = __int_as_float(c0.y), m1 = __int_as_float(c1.y);
        float m2 = __int_as_float(c2.y), m3 = __int_as_float(c3.y);
        fma_h4(acc, u0, m0);
        fma_h4(acc, u1, m1);
        fma_h4(acc, u2, m2);
        fma_h4(acc, u3, m3);
        msum += m0 + m1 + m2 + m3;
    }
    for (; j < e; ++j) {
        int2 cm = csr[j];
        uint2 u = *((const uint2*)(ht + (long long)cm.x * 64) + q);
        float m = __int_as_float(cm.y);
        fma_h4(acc, u, m);
        msum += m;
    }

    const float inv = 1.0f / fmaxf(msum, 1.0f);
    acc.x *= inv; acc.y *= inv; acc.z *= inv; acc.w *= inv;

    // ---- finish: proj(expmap0(relu(logmap0(proj(expmap0(agg)))))) * nm ----
    float ss = acc.x*acc.x + acc.y*acc.y + acc.z*acc.z + acc.w*acc.w;
    float n1 = fmaxf(sqrtf(gsum16(ss)), EPS);
    float t1 = tanhf(clamp_tanh_arg(n1));
    float r1 = t1 / n1;
    acc.x *= r1; acc.y *= r1; acc.z *= r1; acc.w *= r1;
    if (t1 > MAXNORM) {
        float sc = MAXNORM / t1;
        acc.x *= sc; acc.y *= sc; acc.z *= sc; acc.w *= sc;
        t1 = MAXNORM;
    }
    float n2 = fmaxf(t1, EPS);
    float r2 = artanh_clip(n2) / n2;
    acc.x = fmaxf(acc.x * r2, 0.f); acc.y = fmaxf(acc.y * r2, 0.f);
    acc.z = fmaxf(acc.z * r2, 0.f); acc.w = fmaxf(acc.w * r2, 0.f);

    ss = acc.x*acc.x + acc.y*acc.y + acc.z*acc.z + acc.w*acc.w;
    float n3 = fmaxf(sqrtf(gsum16(ss)), EPS);
    float t3 = tanhf(clamp_tanh_arg(n3));
    float r3 = t3 / n3;
    acc.x *= r3; acc.y *= r3; acc.z *= r3; acc.w *= r3;
    if (t3 > MAXNORM) {
        float sc = MAXNORM / t3;
        acc.x *= sc; acc.y *= sc; acc.z *= sc; acc.w *= sc;
        t3 = MAXNORM;
    }

    const float nm = node_mask[nd];
    acc.x *= nm; acc.y *= nm; acc.z *= nm; acc.w *= nm;

    if constexpr (!FUSE) {
        if (valid) ((float4*)((float*)outp + (long long)node * 64))[q] = acc;
    } else {
        // ---- fused next-layer HypLinear + logmap0, fp16 output ----
        float* xrow = &xs[(wv * 4 + ns) * 68];      // wave-private row
        *(float4*)(xrow + (q << 2)) = acc;          // in-wave LDS ordering ok

        float4 mx = make_float4(0.f, 0.f, 0.f, 0.f);
#pragma unroll
        for (int k = 0; k < 64; ++k) {
            float xk = xrow[k];
            const float4 w4 = *(const float4*)&WT[(k << 6) | ((q << 2) ^ ((k & 15) << 2))];
            mx.x = fmaf(w4.x, xk, mx.x); mx.y = fmaf(w4.y, xk, mx.y);
            mx.z = fmaf(w4.z, xk, mx.z); mx.w = fmaf(w4.w, xk, mx.w);
        }

        float xn  = fmaxf(t3 * fabsf(nm), EPS);     // |x| known analytically
        float ssm = mx.x*mx.x + mx.y*mx.y + mx.z*mx.z + mx.w*mx.w;
        float mxn = fmaxf(sqrtf(gsum16(ssm)), EPS);
        float r = tanhf(clamp_tanh_arg(mxn / xn * artanh_clip(xn)));
        float rs = r / mxn;
        float4 hj = make_float4(mx.x * rs, mx.y * rs, mx.z * rs, mx.w * rs);
        float hn = fmaxf(r, EPS);
        if (hn > MAXNORM) {
            float sc = MAXNORM / hn;
            hj.x *= sc; hj.y *= sc; hj.z *= sc; hj.w *= sc;
            hn = MAXNORM;
        }

        float x2 = hn * hn;
        float xy = gsum16(hj.x*hb4.x + hj.y*hb4.y + hj.z*hb4.z + hj.w*hb4.w);
        float ca = 1.0f + 2.0f * xy + y2;
        float cb = 1.0f - x2;
        float iden = 1.0f / fmaxf(1.0f + 2.0f * xy + x2 * y2, EPS);
        hj.x = (ca * hj.x + cb * hb4.x) * iden;
        hj.y = (ca * hj.y + cb * hb4.y) * iden;
        hj.z = (ca * hj.z + cb * hb4.z) * iden;
        hj.w = (ca * hj.w + cb * hb4.w) * iden;

        float ssh = hj.x*hj.x + hj.y*hj.y + hj.z*hj.z + hj.w*hj.w;
        float hn2 = fmaxf(sqrtf(gsum16(ssh)), EPS);
        float sc2 = (hn2 > MAXNORM) ? (MAXNORM / hn2) : 1.0f;
        float hnc = fminf(hn2, MAXNORM);
        float lr = artanh_clip(hnc) / hnc * sc2;    // logmap0 incl. proj scale
        hj.x *= lr; hj.y *= lr; hj.z *= lr; hj.w *= lr;

        if (valid) {
            __half2 p01 = __float22half2_rn(make_float2(hj.x, hj.y));
            __half2 p23 = __float22half2_rn(make_float2(hj.z, hj.w));
            uint2 o;
            o.x = *reinterpret_cast<unsigned*>(&p01);
            o.y = *reinterpret_cast<unsigned*>(&p23);
            *((uint2*)((__half*)outp + (long long)node * 64) + q) = o;
        }
    }
}

extern "C" void kernel_launch(void* const* d_in, const int* in_sizes, int n_in,
                              void* d_out, int out_size, void* d_ws, size_t ws_size,
                              hipStream_t stream) {
    const float* h         = (const float*)d_in[0];
    // d_in[1] = distances (unused by the reference computation)
    const int*   edges     = (const int*)d_in[2];     // [2, E] int32
    const float* node_mask = (const float*)d_in[3];
    const float* edge_mask = (const float*)d_in[4];
    const float* W0        = (const float*)d_in[5];
    const float* b0        = (const float*)d_in[6];
    const float* W1        = (const float*)d_in[7];
    const float* b1        = (const float*)d_in[8];
    float* out = (float*)d_out;

    const int N = in_sizes[0] / 64;
    const int E = in_sizes[4];          // edge_mask is [E,1]
    const int* rows = edges;
    const int* cols = edges + E;

    const int NB  = (N + 255) >> 8;     // coarse buckets (row>>8), 196 for 50K
    const int EPB = (E + HGRID - 1) / HGRID;

    size_t nd = (size_t)N * 64;
    char* ws = (char*)d_ws;
    __half* B1         = (__half*)ws; ws += nd * sizeof(__half);        // ht1 fp16
    __half* B2         = (__half*)ws; ws += nd * sizeof(__half);        // ht2 fp16
    int2*  coarse      = (int2*)ws;   ws += (size_t)E * sizeof(int2);
    int2*  csr         = (int2*)ws;   ws += (size_t)E * sizeof(int2);
    int*   histB       = (int*)ws;    ws += (size_t)HGRID * NB * sizeof(int);
    int*   tot         = (int*)ws;    ws += (size_t)NB * sizeof(int);
    int*   bucket_base = (int*)ws;    ws += (size_t)(NB + 1) * sizeof(int);
    int*   row_start   = (int*)ws;    ws += (size_t)(N + 1) * sizeof(int);

    const int TGRID = 1024;
    const int NGRID = (N + 15) / 16;

    // K1: coarse histogram (no global atomics) + layer-1 transform
    hist_transform_kernel<<<HGRID + TGRID, 256, 0, stream>>>(
        rows, histB, E, EPB, NB, h, W0, b0, B1, N);

    // K2a: per-bucket scan of per-block counts (parallel over buckets)
    scan_bucket_kernel<<<NB, HGRID, 0, stream>>>(histB, tot, NB);

    // K2b: tiny scan of bucket totals
    scan_base_kernel<<<1, 256, 0, stream>>>(tot, bucket_base, NB);

    // K3: coarse scatter with LDS cursors (contiguous per-block chunks)
    coarse_scatter_kernel<<<HGRID, 256, 0, stream>>>(
        rows, cols, edge_mask, histB, bucket_base, coarse, E, EPB, NB);

    // K4: fine partition -> CSR + row_start (fully coalesced global I/O)
    fine_kernel<<<NB, 1024, 0, stream>>>(
        coarse, bucket_base, csr, row_start, N, E);

    // layer-1 agg+finish fused with layer-2 HypLinear -> ht2 (fp16)
    gather_kernel<true><<<NGRID, 256, 0, stream>>>(
        B1, csr, row_start, node_mask, W1, b1, B2, N);

    // layer-2 agg+finish -> final fp32 output
    gather_kernel<false><<<NGRID, 256, 0, stream>>>(
        B2, csr, row_start, node_mask, nullptr, nullptr, out, N);
}

// Round 11
// 206.494 us; speedup vs baseline: 1.6316x; 1.0759x over previous
//
#include <hip/hip_runtime.h>
#include <hip/hip_fp16.h>

#define EPS      1e-7f
#define MAX_TANH 15.0f
#define MAXNORM  0.99999f   // (1 - 1e-5) / sqrt(c), c = 1
#define ART_CLIP 0.99999f   // 1 - 1e-5
#define HGRID    512        // coarse-partition blocks (histogram & scatter)
#define RPB      128        // rows per coarse bucket (row >> 7)
#define CAPF     4096       // fine-pass LDS staging (mean ~3061, +13 sigma)
#define NBMAX    512

__device__ __forceinline__ float wave_sum64(float v) {
#pragma unroll
    for (int o = 32; o > 0; o >>= 1) v += __shfl_xor(v, o, 64);
    return v;
}

// sum across an aligned 16-lane group
__device__ __forceinline__ float gsum16(float v) {
    v += __shfl_xor(v, 1, 64);
    v += __shfl_xor(v, 2, 64);
    v += __shfl_xor(v, 4, 64);
    v += __shfl_xor(v, 8, 64);
    return v;
}

__device__ __forceinline__ float clamp_tanh_arg(float x) {
    return fminf(fmaxf(x, -MAX_TANH), MAX_TANH);
}

__device__ __forceinline__ float artanh_clip(float x) {
    x = fminf(fmaxf(x, -ART_CLIP), ART_CLIP);
    return 0.5f * logf((1.0f + x) / (1.0f - x));
}

// fma a half4 (as uint2) * m into acc
__device__ __forceinline__ void fma_h4(float4& acc, uint2 u, float m) {
    float2 f01 = __half22float2(*reinterpret_cast<__half2*>(&u.x));
    float2 f23 = __half22float2(*reinterpret_cast<__half2*>(&u.y));
    acc.x = fmaf(f01.x, m, acc.x); acc.y = fmaf(f01.y, m, acc.y);
    acc.z = fmaf(f23.x, m, acc.z); acc.w = fmaf(f23.y, m, acc.w);
}

// ---------------------------------------------------------------------------
// K1 (fat). Blocks [0, HGRID): coarse histogram of row>>7 into LDS, coalesced
// write of per-block counts. Blocks [HGRID, ...): layer-1 transform (fp16):
//   ht = logmap0(proj(mobius_add(proj(mobius_matvec(W,x)), hyp_bias)))
// ---------------------------------------------------------------------------
__global__ __launch_bounds__(256) void hist_transform_kernel(
    const int* __restrict__ rows, int* __restrict__ histB,
    int n_edges, int epb, int nb,
    const float* __restrict__ x, const float* __restrict__ W,
    const float* __restrict__ b, __half* __restrict__ ht, int n_nodes)
{
    __shared__ float WT[64 * 65];
    __shared__ float xs[4][64];
    __shared__ int hh[NBMAX];

    if (blockIdx.x < HGRID) {
        const int b0 = blockIdx.x * epb;
        const int b1 = min(b0 + epb, n_edges);
        for (int j = threadIdx.x; j < nb; j += 256) hh[j] = 0;
        __syncthreads();
        for (int i = b0 + threadIdx.x; i < b1; i += 256)
            atomicAdd(&hh[rows[i] >> 7], 1);
        __syncthreads();
        for (int j = threadIdx.x; j < nb; j += 256)
            histB[blockIdx.x * nb + j] = hh[j];
        return;
    }

    // ---------------- transform half ----------------
    const int t = threadIdx.x;
    const int lane = t & 63;
    const int wv = t >> 6;
    const int bid = blockIdx.x - HGRID;
    const int tgrid = gridDim.x - HGRID;

#pragma unroll
    for (int r = 0; r < 16; ++r) {
        int idx = r * 256 + t;
        WT[(idx & 63) * 65 + (idx >> 6)] = W[idx];
    }
    __syncthreads();

    // hyp_bias = proj(expmap0(b)); |expmap0(b)| = tanh(|b|)
    float bj = b[lane];
    float bn = fmaxf(sqrtf(wave_sum64(bj * bj)), EPS);
    float tb = tanhf(clamp_tanh_arg(bn));
    float hb = tb * bj / bn;
    if (tb > MAXNORM) { hb *= MAXNORM / tb; tb = MAXNORM; }
    const float y2 = tb * tb;

    for (long long base = (long long)bid * 4; base < n_nodes;
         base += (long long)tgrid * 4) {
        long long node = base + wv;
        float xj = 0.0f;
        if (node < n_nodes) xj = x[node * 64 + lane];
        xs[wv][lane] = xj;

        float mxj = 0.0f;
#pragma unroll
        for (int k = 0; k < 64; ++k)
            mxj = fmaf(xs[wv][k], WT[k * 65 + lane], mxj);

        float xn  = fmaxf(sqrtf(wave_sum64(xj * xj)), EPS);
        float mxn = fmaxf(sqrtf(wave_sum64(mxj * mxj)), EPS);
        float r = tanhf(clamp_tanh_arg(mxn / xn * artanh_clip(xn)));  // = |h|
        float hj = r * mxj / mxn;
        float hn = fmaxf(r, EPS);
        if (hn > MAXNORM) { hj *= MAXNORM / hn; hn = MAXNORM; }

        float x2 = hn * hn;
        float xy = wave_sum64(hj * hb);
        float num = (1.0f + 2.0f * xy + y2) * hj + (1.0f - x2) * hb;
        float den = fmaxf(1.0f + 2.0f * xy + x2 * y2, EPS);
        hj = num / den;

        float hn2 = fmaxf(sqrtf(wave_sum64(hj * hj)), EPS);
        if (hn2 > MAXNORM) { hj *= MAXNORM / hn2; hn2 = MAXNORM; }

        float htj = artanh_clip(hn2) * hj / hn2;   // logmap0

        if (node < n_nodes) ht[node * 64 + lane] = __float2half(htj);
    }
}

// ---------------------------------------------------------------------------
// K2a: one block per coarse bucket; scan its HGRID per-block counts in place
// into within-bucket exclusive offsets; write bucket total.
// ---------------------------------------------------------------------------
__global__ __launch_bounds__(HGRID) void scan_bucket_kernel(
    int* __restrict__ histB, int* __restrict__ tot, int nb)
{
    __shared__ int wsum[8];
    const int b = blockIdx.x;
    const int t = threadIdx.x;
    const int lane = t & 63, wid = t >> 6;
    int v = histB[t * nb + b];
    int incl = v;
#pragma unroll
    for (int o = 1; o < 64; o <<= 1) {
        int tt = __shfl_up(incl, o, 64);
        if (lane >= o) incl += tt;
    }
    if (lane == 63) wsum[wid] = incl;
    __syncthreads();
    if (wid == 0 && lane < 8) {
        int ws = wsum[lane];
#pragma unroll
        for (int o = 1; o < 8; o <<= 1) {
            int tt = __shfl_up(ws, o, 64);
            if (lane >= o) ws += tt;
        }
        wsum[lane] = ws;
    }
    __syncthreads();
    int base = (wid > 0) ? wsum[wid - 1] : 0;
    histB[t * nb + b] = base + incl - v;
    if (t == HGRID - 1) tot[b] = base + incl;
}

// ---------------------------------------------------------------------------
// K2b: single-block scan of bucket totals -> bucket_base[nb+1]. nb <= 512.
// ---------------------------------------------------------------------------
__global__ __launch_bounds__(NBMAX) void scan_base_kernel(
    const int* __restrict__ tot, int* __restrict__ bucket_base, int nb)
{
    __shared__ int s[NBMAX];
    const int t = threadIdx.x;
    int v = (t < nb) ? tot[t] : 0;
    s[t] = v;
    __syncthreads();
    for (int off = 1; off < NBMAX; off <<= 1) {
        int u = (t >= off) ? s[t - off] : 0;
        __syncthreads();
        s[t] += u;
        __syncthreads();
    }
    if (t < nb) bucket_base[t] = s[t] - v;
    if (t == nb - 1) bucket_base[nb] = s[t];
}

// ---------------------------------------------------------------------------
// K3: coarse scatter via LDS cursors (no global atomics). cursor = bucket
// base + within-bucket per-block offset. Record: x=(row<<16)|col, y=mask.
// ---------------------------------------------------------------------------
__global__ __launch_bounds__(256) void coarse_scatter_kernel(
    const int* __restrict__ rows, const int* __restrict__ cols,
    const float* __restrict__ edge_mask, const int* __restrict__ off,
    const int* __restrict__ bucket_base,
    int2* __restrict__ coarse, int n_edges, int epb, int nb)
{
    __shared__ int cur[NBMAX];
    const int b0 = blockIdx.x * epb;
    const int b1 = min(b0 + epb, n_edges);
    for (int j = threadIdx.x; j < nb; j += 256)
        cur[j] = bucket_base[j] + off[blockIdx.x * nb + j];
    __syncthreads();
    for (int i = b0 + threadIdx.x; i < b1; i += 256) {
        int r = rows[i], c = cols[i];
        float m = edge_mask[i];
        int pos = atomicAdd(&cur[r >> 7], 1);
        coarse[pos] = make_int2((r << 16) | c, __float_as_int(m));
    }
}

// ---------------------------------------------------------------------------
// K4 fused: fine partition + layer-1 gather/finish + layer-2 HypLinear.
// One block per coarse bucket (~3061 edges, 128 rows):
//   LDS hist -> LDS scan -> LDS scatter (sorted edges stay IN LDS)
//   -> packed csr4 write-out (col | fp16 mask) + row_start for layer 2
//   -> gather straight from LDS edge records (random global ht1 reads)
//   -> finish -> fused HypLinear(W1,b1) + logmap0 -> ht2 (fp16).
// ---------------------------------------------------------------------------
__global__ __launch_bounds__(1024) void fine_gather_kernel(
    const int2* __restrict__ coarse, const int* __restrict__ bucket_base,
    const __half* __restrict__ ht1, const float* __restrict__ node_mask,
    const float* __restrict__ W, const float* __restrict__ bvec,
    unsigned* __restrict__ csr4, int* __restrict__ row_start,
    __half* __restrict__ ht2, int n_nodes, int n_edges)
{
    __shared__ int hh[RPB], incl[RPB], curs[RPB];
    __shared__ int2 outE[CAPF];                // 32 KB
    __shared__ float WT[4096];                 // 16 KB, xor-swizzled W^T
    __shared__ float xs[64 * 68];              // 17 KB, matvec round-trip

    const int t = threadIdx.x;
    const int b = blockIdx.x;
    const int q = t & 15;                      // dim quad: dims 4q..4q+3
    const int g = t >> 4;                      // node group 0..63
    const int bbase = bucket_base[b];
    const int n_e = bucket_base[b + 1] - bbase;

    // stage W^T (xor-swizzled for conflict-free float4 reads) + hyp_bias
#pragma unroll
    for (int r = 0; r < 4; ++r) {
        int idx = r * 1024 + t;
        int j = idx >> 6, k = idx & 63;
        WT[(k << 6) | (j ^ ((k & 15) << 2))] = W[idx];
    }
    float4 b4 = ((const float4*)bvec)[q];
    float ssb = b4.x*b4.x + b4.y*b4.y + b4.z*b4.z + b4.w*b4.w;
    float bn = fmaxf(sqrtf(gsum16(ssb)), EPS);
    float tb = tanhf(clamp_tanh_arg(bn));
    float sb = tb / bn;
    float4 hb4 = make_float4(b4.x * sb, b4.y * sb, b4.z * sb, b4.w * sb);
    if (tb > MAXNORM) {
        float sc = MAXNORM / tb;
        hb4.x *= sc; hb4.y *= sc; hb4.z *= sc; hb4.w *= sc;
        tb = MAXNORM;
    }
    const float y2 = tb * tb;

    // ---- fine partition into LDS ----
    if (t < RPB) hh[t] = 0;
    __syncthreads();
    for (int i = t; i < n_e; i += 1024)
        atomicAdd(&hh[(coarse[bbase + i].x >> 16) & (RPB - 1)], 1);
    __syncthreads();
    if (t < RPB) incl[t] = hh[t];
    __syncthreads();
    for (int off = 1; off < RPB; off <<= 1) {
        int v = (t < RPB && t >= off) ? incl[t - off] : 0;
        __syncthreads();
        if (t < RPB) incl[t] += v;
        __syncthreads();
    }
    if (t < RPB) {
        curs[t] = incl[t] - hh[t];
        int grow = (b << 7) + t;
        if (grow < n_nodes) row_start[grow] = bbase + incl[t] - hh[t];
    }
    if (b == gridDim.x - 1 && t == 0) row_start[n_nodes] = n_edges;
    __syncthreads();
    for (int i = t; i < n_e; i += 1024) {
        int2 rec = coarse[bbase + i];
        int slot = atomicAdd(&curs[(rec.x >> 16) & (RPB - 1)], 1);
        if (slot < CAPF) outE[slot] = make_int2(rec.x & 0xffff, rec.y);
    }
    __syncthreads();

    // ---- packed csr for layer 2 (coalesced) ----
    const int lim = min(n_e, CAPF);
    for (int i = t; i < lim; i += 1024) {
        int2 rec = outE[i];
        __half hm = __float2half(__int_as_float(rec.y));
        csr4[bbase + i] = (unsigned)rec.x |
                          ((unsigned)*reinterpret_cast<unsigned short*>(&hm) << 16);
    }

    // ---- gather + finish + HypLinear for this bucket's 128 nodes ----
#pragma unroll
    for (int batch = 0; batch < 2; ++batch) {
        const int ln = batch * 64 + g;               // local row 0..127
        const int node = (b << 7) + ln;
        const bool valid = node < n_nodes;
        const int nd = valid ? node : (n_nodes - 1);
        const int s0 = incl[ln] - hh[ln];
        const int e0 = incl[ln];

        float4 acc = make_float4(0.f, 0.f, 0.f, 0.f);
        float msum = 0.f;
        int j = s0;
        for (; j + 4 <= e0; j += 4) {
            int2 r0 = outE[j], r1 = outE[j + 1], r2 = outE[j + 2], r3 = outE[j + 3];
            uint2 u0 = *((const uint2*)(ht1 + (long long)r0.x * 64) + q);
            uint2 u1 = *((const uint2*)(ht1 + (long long)r1.x * 64) + q);
            uint2 u2 = *((const uint2*)(ht1 + (long long)r2.x * 64) + q);
            uint2 u3 = *((const uint2*)(ht1 + (long long)r3.x * 64) + q);
            float m0 = __int_as_float(r0.y), m1 = __int_as_float(r1.y);
            float m2 = __int_as_float(r2.y), m3 = __int_as_float(r3.y);
            fma_h4(acc, u0, m0); fma_h4(acc, u1, m1);
            fma_h4(acc, u2, m2); fma_h4(acc, u3, m3);
            msum += m0 + m1 + m2 + m3;
        }
        for (; j < e0; ++j) {
            int2 rec = outE[j];
            uint2 u = *((const uint2*)(ht1 + (long long)rec.x * 64) + q);
            float m = __int_as_float(rec.y);
            fma_h4(acc, u, m);
            msum += m;
        }

        const float inv = 1.0f / fmaxf(msum, 1.0f);
        acc.x *= inv; acc.y *= inv; acc.z *= inv; acc.w *= inv;

        // finish: proj(expmap0(relu(logmap0(proj(expmap0(agg)))))) * nm
        float ss = acc.x*acc.x + acc.y*acc.y + acc.z*acc.z + acc.w*acc.w;
        float n1 = fmaxf(sqrtf(gsum16(ss)), EPS);
        float t1 = tanhf(clamp_tanh_arg(n1));
        float r1 = t1 / n1;
        acc.x *= r1; acc.y *= r1; acc.z *= r1; acc.w *= r1;
        if (t1 > MAXNORM) {
            float sc = MAXNORM / t1;
            acc.x *= sc; acc.y *= sc; acc.z *= sc; acc.w *= sc;
            t1 = MAXNORM;
        }
        float n2 = fmaxf(t1, EPS);
        float r2s = artanh_clip(n2) / n2;
        acc.x = fmaxf(acc.x * r2s, 0.f); acc.y = fmaxf(acc.y * r2s, 0.f);
        acc.z = fmaxf(acc.z * r2s, 0.f); acc.w = fmaxf(acc.w * r2s, 0.f);

        ss = acc.x*acc.x + acc.y*acc.y + acc.z*acc.z + acc.w*acc.w;
        float n3 = fmaxf(sqrtf(gsum16(ss)), EPS);
        float t3 = tanhf(clamp_tanh_arg(n3));
        float r3 = t3 / n3;
        acc.x *= r3; acc.y *= r3; acc.z *= r3; acc.w *= r3;
        if (t3 > MAXNORM) {
            float sc = MAXNORM / t3;
            acc.x *= sc; acc.y *= sc; acc.z *= sc; acc.w *= sc;
            t3 = MAXNORM;
        }

        const float nm = node_mask[nd];
        acc.x *= nm; acc.y *= nm; acc.z *= nm; acc.w *= nm;

        // fused next-layer HypLinear + logmap0 -> ht2 (fp16)
        float* xrow = &xs[g * 68];                  // group-private row
        *(float4*)(xrow + (q << 2)) = acc;          // in-wave LDS ordering ok

        float4 mx = make_float4(0.f, 0.f, 0.f, 0.f);
#pragma unroll
        for (int k = 0; k < 64; ++k) {
            float xk = xrow[k];
            const float4 w4 = *(const float4*)&WT[(k << 6) | ((q << 2) ^ ((k & 15) << 2))];
            mx.x = fmaf(w4.x, xk, mx.x); mx.y = fmaf(w4.y, xk, mx.y);
            mx.z = fmaf(w4.z, xk, mx.z); mx.w = fmaf(w4.w, xk, mx.w);
        }

        float xn  = fmaxf(t3 * fabsf(nm), EPS);     // |x| known analytically
        float ssm = mx.x*mx.x + mx.y*mx.y + mx.z*mx.z + mx.w*mx.w;
        float mxn = fmaxf(sqrtf(gsum16(ssm)), EPS);
        float r = tanhf(clamp_tanh_arg(mxn / xn * artanh_clip(xn)));
        float rs = r / mxn;
        float4 hj = make_float4(mx.x * rs, mx.y * rs, mx.z * rs, mx.w * rs);
        float hn = fmaxf(r, EPS);
        if (hn > MAXNORM) {
            float sc = MAXNORM / hn;
            hj.x *= sc; hj.y *= sc; hj.z *= sc; hj.w *= sc;
            hn = MAXNORM;
        }

        float x2 = hn * hn;
        float xy = gsum16(hj.x*hb4.x + hj.y*hb4.y + hj.z*hb4.z + hj.w*hb4.w);
        float ca = 1.0f + 2.0f * xy + y2;
        float cb = 1.0f - x2;
        float iden = 1.0f / fmaxf(1.0f + 2.0f * xy + x2 * y2, EPS);
        hj.x = (ca * hj.x + cb * hb4.x) * iden;
        hj.y = (ca * hj.y + cb * hb4.y) * iden;
        hj.z = (ca * hj.z + cb * hb4.z) * iden;
        hj.w = (ca * hj.w + cb * hb4.w) * iden;

        float ssh = hj.x*hj.x + hj.y*hj.y + hj.z*hj.z + hj.w*hj.w;
        float hn2 = fmaxf(sqrtf(gsum16(ssh)), EPS);
        float sc2 = (hn2 > MAXNORM) ? (MAXNORM / hn2) : 1.0f;
        float hnc = fminf(hn2, MAXNORM);
        float lr = artanh_clip(hnc) / hnc * sc2;    // logmap0 incl. proj scale
        hj.x *= lr; hj.y *= lr; hj.z *= lr; hj.w *= lr;

        if (valid) {
            __half2 p01 = __float22half2_rn(make_float2(hj.x, hj.y));
            __half2 p23 = __float22half2_rn(make_float2(hj.z, hj.w));
            uint2 o;
            o.x = *reinterpret_cast<unsigned*>(&p01);
            o.y = *reinterpret_cast<unsigned*>(&p23);
            *((uint2*)(ht2 + (long long)node * 64) + q) = o;
        }
    }
}

// ---------------------------------------------------------------------------
// G2: layer-2 gather + finish -> fp32 output. 4 nodes/wave, 16 lanes/node,
// packed 4 B csr records (col | fp16 mask).
// ---------------------------------------------------------------------------
__global__ __launch_bounds__(256) void gather2_kernel(
    const __half* __restrict__ ht, const unsigned* __restrict__ csr4,
    const int* __restrict__ row_start, const float* __restrict__ node_mask,
    float* __restrict__ outp, int n_nodes)
{
    const int t = threadIdx.x;
    const int lane = t & 63;
    const int wv = t >> 6;
    const int ns = lane >> 4;
    const int q  = lane & 15;

    const int node = blockIdx.x * 16 + (wv << 2) + ns;
    const bool valid = node < n_nodes;
    const int nd = valid ? node : (n_nodes - 1);
    const int s = row_start[nd];
    const int e = row_start[nd + 1];

    float4 acc = make_float4(0.f, 0.f, 0.f, 0.f);
    float msum = 0.f;
    int j = s;
    for (; j + 4 <= e; j += 4) {
        unsigned v0 = csr4[j], v1 = csr4[j + 1], v2 = csr4[j + 2], v3 = csr4[j + 3];
        uint2 u0 = *((const uint2*)(ht + (long long)(v0 & 0xffffu) * 64) + q);
        uint2 u1 = *((const uint2*)(ht + (long long)(v1 & 0xffffu) * 64) + q);
        uint2 u2 = *((const uint2*)(ht + (long long)(v2 & 0xffffu) * 64) + q);
        uint2 u3 = *((const uint2*)(ht + (long long)(v3 & 0xffffu) * 64) + q);
        unsigned short h0 = v0 >> 16, h1 = v1 >> 16, h2 = v2 >> 16, h3 = v3 >> 16;
        float m0 = __half2float(*reinterpret_cast<__half*>(&h0));
        float m1 = __half2float(*reinterpret_cast<__half*>(&h1));
        float m2 = __half2float(*reinterpret_cast<__half*>(&h2));
        float m3 = __half2float(*reinterpret_cast<__half*>(&h3));
        fma_h4(acc, u0, m0); fma_h4(acc, u1, m1);
        fma_h4(acc, u2, m2); fma_h4(acc, u3, m3);
        msum += m0 + m1 + m2 + m3;
    }
    for (; j < e; ++j) {
        unsigned v = csr4[j];
        uint2 u = *((const uint2*)(ht + (long long)(v & 0xffffu) * 64) + q);
        unsigned short hb = v >> 16;
        float m = __half2float(*reinterpret_cast<__half*>(&hb));
        fma_h4(acc, u, m);
        msum += m;
    }

    const float inv = 1.0f / fmaxf(msum, 1.0f);
    acc.x *= inv; acc.y *= inv; acc.z *= inv; acc.w *= inv;

    float ss = acc.x*acc.x + acc.y*acc.y + acc.z*acc.z + acc.w*acc.w;
    float n1 = fmaxf(sqrtf(gsum16(ss)), EPS);
    float t1 = tanhf(clamp_tanh_arg(n1));
    float r1 = t1 / n1;
    acc.x *= r1; acc.y *= r1; acc.z *= r1; acc.w *= r1;
    if (t1 > MAXNORM) {
        float sc = MAXNORM / t1;
        acc.x *= sc; acc.y *= sc; acc.z *= sc; acc.w *= sc;
        t1 = MAXNORM;
    }
    float n2 = fmaxf(t1, EPS);
    float r2 = artanh_clip(n2) / n2;
    acc.x = fmaxf(acc.x * r2, 0.f); acc.y = fmaxf(acc.y * r2, 0.f);
    acc.z = fmaxf(acc.z * r2, 0.f); acc.w = fmaxf(acc.w * r2, 0.f);

    ss = acc.x*acc.x + acc.y*acc.y + acc.z*acc.z + acc.w*acc.w;
    float n3 = fmaxf(sqrtf(gsum16(ss)), EPS);
    float t3 = tanhf(clamp_tanh_arg(n3));
    float r3 = t3 / n3;
    acc.x *= r3; acc.y *= r3; acc.z *= r3; acc.w *= r3;
    if (t3 > MAXNORM) {
        float sc = MAXNORM / t3;
        acc.x *= sc; acc.y *= sc; acc.z *= sc; acc.w *= sc;
        t3 = MAXNORM;
    }

    const float nm = node_mask[nd];
    acc.x *= nm; acc.y *= nm; acc.z *= nm; acc.w *= nm;

    if (valid) ((float4*)(outp + (long long)node * 64))[q] = acc;
}

extern "C" void kernel_launch(void* const* d_in, const int* in_sizes, int n_in,
                              void* d_out, int out_size, void* d_ws, size_t ws_size,
                              hipStream_t stream) {
    const float* h         = (const float*)d_in[0];
    // d_in[1] = distances (unused by the reference computation)
    const int*   edges     = (const int*)d_in[2];     // [2, E] int32
    const float* node_mask = (const float*)d_in[3];
    const float* edge_mask = (const float*)d_in[4];
    const float* W0        = (const float*)d_in[5];
    const float* b0        = (const float*)d_in[6];
    const float* W1        = (const float*)d_in[7];
    const float* b1        = (const float*)d_in[8];
    float* out = (float*)d_out;

    const int N = in_sizes[0] / 64;
    const int E = in_sizes[4];          // edge_mask is [E,1]
    const int* rows = edges;
    const int* cols = edges + E;

    const int NB  = (N + RPB - 1) / RPB;     // 391 coarse buckets
    const int EPB = (E + HGRID - 1) / HGRID;

    size_t nd = (size_t)N * 64;
    char* ws = (char*)d_ws;
    __half*   B1          = (__half*)ws;   ws += nd * sizeof(__half);   // ht1
    __half*   B2          = (__half*)ws;   ws += nd * sizeof(__half);   // ht2
    int2*     coarse      = (int2*)ws;     ws += (size_t)E * sizeof(int2);
    unsigned* csr4        = (unsigned*)ws; ws += (size_t)E * sizeof(unsigned);
    int*      histB       = (int*)ws;      ws += (size_t)HGRID * NB * sizeof(int);
    int*      tot         = (int*)ws;      ws += (size_t)NB * sizeof(int);
    int*      bucket_base = (int*)ws;      ws += (size_t)(NB + 1) * sizeof(int);
    int*      row_start   = (int*)ws;      ws += (size_t)(N + 1) * sizeof(int);

    const int TGRID = 1024;
    const int NGRID = (N + 15) / 16;

    // K1: coarse histogram + layer-1 transform (fp16 ht1)
    hist_transform_kernel<<<HGRID + TGRID, 256, 0, stream>>>(
        rows, histB, E, EPB, NB, h, W0, b0, B1, N);

    // K2a/K2b: parallel scans
    scan_bucket_kernel<<<NB, HGRID, 0, stream>>>(histB, tot, NB);
    scan_base_kernel<<<1, NBMAX, 0, stream>>>(tot, bucket_base, NB);

    // K3: coarse scatter (LDS cursors, contiguous chunks)
    coarse_scatter_kernel<<<HGRID, 256, 0, stream>>>(
        rows, cols, edge_mask, histB, bucket_base, coarse, E, EPB, NB);

    // K4 fused: fine partition + layer-1 gather/finish + layer-2 HypLinear
    //           -> ht2 (fp16) + packed csr4 + row_start
    fine_gather_kernel<<<NB, 1024, 0, stream>>>(
        coarse, bucket_base, B1, node_mask, W1, b1, csr4, row_start, B2, N, E);

    // G2: layer-2 gather + finish -> fp32 output
    gather2_kernel<<<NGRID, 256, 0, stream>>>(
        B2, csr4, row_start, node_mask, out, N);
}